// Round 1
// baseline (330.580 us; speedup 1.0000x reference)
//
#include <hip/hip_runtime.h>
#include <hip/hip_bf16.h>
#include <cstdint>

#define T_TOK 8192
#define HID   1024
#define NE    9      // 8 routed experts + 1 shared (e=8, weight 1.0)
#define ISZ   512

#define BM 128
#define BN 128
#define BK 32

typedef unsigned short u16;
typedef unsigned int   u32;
typedef __attribute__((ext_vector_type(8))) short short8;
typedef __attribute__((ext_vector_type(4))) float f32x4;

__device__ __forceinline__ u16 f2bf(float f) {
  u32 u = __builtin_bit_cast(u32, f);
  return (u16)((u + 0x7fffu + ((u >> 16) & 1u)) >> 16);
}

#define STAGE(gp, lp) __builtin_amdgcn_global_load_lds( \
    (__attribute__((address_space(1))) u32*)(gp),       \
    (__attribute__((address_space(3))) u32*)(lp), 16, 0, 0)

// ---------------- conversions ----------------
__global__ void k_cvt_x(const float* __restrict__ x, u16* __restrict__ xb, int n4) {
  int i = blockIdx.x * blockDim.x + threadIdx.x;
  if (i >= n4) return;
  float4 v = ((const float4*)x)[i];
  ushort4 o;
  o.x = f2bf(v.x); o.y = f2bf(v.y); o.z = f2bf(v.z); o.w = f2bf(v.w);
  ((ushort4*)xb)[i] = o;
}

// w_experts_gate_up [8][1024][1024] + w_shared_gate_up [1024][1024]
// -> dst [9][1024(colp)][1024(h)]  (transposed, gate/up interleaved per 16 cols)
__global__ void k_cvt_wgup(const float* __restrict__ wexp, const float* __restrict__ wsh,
                           u16* __restrict__ dst) {
  __shared__ float tile[32][33];
  const int e = blockIdx.z;
  const float* src = (e < 8) ? (wexp + (size_t)e * HID * 1024) : wsh;
  const int c0 = blockIdx.x * 32, h0 = blockIdx.y * 32;
  const int tx = threadIdx.x, ty = threadIdx.y;
  for (int i = ty; i < 32; i += 8)
    tile[i][tx] = src[(size_t)(h0 + i) * 1024 + c0 + tx];   // tile[h_loc][c_loc]
  __syncthreads();
  for (int j = ty; j < 32; j += 8) {
    int c = c0 + j;
    int i = (c < 512) ? c : (c - 512);
    int colp = ((i >> 4) * 32) + ((c < 512) ? 0 : 16) + (i & 15);
    dst[((size_t)e * 1024 + colp) * HID + h0 + tx] = f2bf(tile[tx][j]);
  }
}

// w_experts_down [8][512][1024] + w_shared_down [512][1024]
// -> dst [9][1024(h_out)][512(i)]  (transposed)
__global__ void k_cvt_wdown(const float* __restrict__ wexp, const float* __restrict__ wsh,
                            u16* __restrict__ dst) {
  __shared__ float tile[32][33];
  const int e = blockIdx.z;
  const float* src = (e < 8) ? (wexp + (size_t)e * ISZ * HID) : wsh;
  const int h0 = blockIdx.x * 32, i0 = blockIdx.y * 32;
  const int tx = threadIdx.x, ty = threadIdx.y;
  for (int a = ty; a < 32; a += 8)
    tile[a][tx] = src[(size_t)(i0 + a) * HID + h0 + tx];    // tile[i_loc][h_loc]
  __syncthreads();
  for (int j = ty; j < 32; j += 8)
    dst[((size_t)e * HID + h0 + j) * ISZ + i0 + tx] = f2bf(tile[tx][j]);
}

// ---------------- router ----------------
__global__ void k_router(const float* __restrict__ x, const float* __restrict__ wg,
                         float* __restrict__ cw) {
  const int t = blockIdx.x;
  const int l = threadIdx.x;
  float a[8] = {0, 0, 0, 0, 0, 0, 0, 0};
  const float* xr = x + (size_t)t * HID;
#pragma unroll
  for (int j = 0; j < HID / 64; ++j) {
    const int h = j * 64 + l;
    const float xv = xr[h];
    const float4 w0 = *(const float4*)&wg[h * 8];
    const float4 w1 = *(const float4*)&wg[h * 8 + 4];
    a[0] += xv * w0.x; a[1] += xv * w0.y; a[2] += xv * w0.z; a[3] += xv * w0.w;
    a[4] += xv * w1.x; a[5] += xv * w1.y; a[6] += xv * w1.z; a[7] += xv * w1.w;
  }
#pragma unroll
  for (int off = 32; off >= 1; off >>= 1) {
#pragma unroll
    for (int e2 = 0; e2 < 8; ++e2) a[e2] += __shfl_xor(a[e2], off);
  }
  if (l == 0) {
    int ia = 0;
#pragma unroll
    for (int e2 = 1; e2 < 8; ++e2) if (a[e2] > a[ia]) ia = e2;
    int ib = (ia == 0) ? 1 : 0;
#pragma unroll
    for (int e2 = 0; e2 < 8; ++e2) if (e2 != ia && a[e2] > a[ib]) ib = e2;
    float wa = 1.f / (1.f + expf(a[ib] - a[ia]));  // renormalized softmax top-2
    float wb = 1.f - wa;
    float* row = cw + (size_t)t * NE;
#pragma unroll
    for (int e2 = 0; e2 < 8; ++e2) row[e2] = (e2 == ia) ? wa : ((e2 == ib) ? wb : 0.f);
    row[8] = 1.f;
  }
}

// ---------------- GEMM1: gu = xb @ wgupT[e]; act = silu(g)*u * cw ----------------
__global__ __launch_bounds__(256) void k_gemm_gu(
    const u16* __restrict__ xb,     // [T][H] bf16
    const u16* __restrict__ wgupT,  // [NE][1024][H] bf16 (B^T, interleaved cols)
    const float* __restrict__ cw,   // [T][NE]
    u16* __restrict__ act)          // [NE][T][ISZ] bf16 (pre-scaled by cw)
{
  __shared__ __align__(16) u16 As[BM * BK];
  __shared__ __align__(16) u16 Bs[BN * BK];
  __shared__ float cws[BM];

  const int tid = threadIdx.x;
  const int w = tid >> 6, l = tid & 63;
  const int e = blockIdx.z;
  const int brow = blockIdx.x * BM;
  const int bcol = blockIdx.y * BN;

  if (tid < BM) cws[tid] = cw[(size_t)(brow + tid) * NE + e];

  const int sub = l >> 2;        // row within 16-row chunk
  const int kc  = (l & 3) * 8;   // k element offset

  const u16* ga0 = xb + (size_t)(brow + (w * 2 + 0) * 16 + sub) * HID + kc;
  const u16* ga1 = xb + (size_t)(brow + (w * 2 + 1) * 16 + sub) * HID + kc;
  const u16* gb0 = wgupT + ((size_t)e * 1024 + bcol + (w * 2 + 0) * 16 + sub) * HID + kc;
  const u16* gb1 = wgupT + ((size_t)e * 1024 + bcol + (w * 2 + 1) * 16 + sub) * HID + kc;

  u16* la0 = &As[(w * 2 + 0) * 16 * BK];
  u16* la1 = &As[(w * 2 + 1) * 16 * BK];
  u16* lb0 = &Bs[(w * 2 + 0) * 16 * BK];
  u16* lb1 = &Bs[(w * 2 + 1) * 16 * BK];

  const int wm = w >> 1, wn = w & 1;
  const int fr = l & 15, fg = l >> 4;

  f32x4 acc[4][4];
#pragma unroll
  for (int m = 0; m < 4; ++m)
#pragma unroll
    for (int n = 0; n < 4; ++n) acc[m][n] = (f32x4){0.f, 0.f, 0.f, 0.f};

  for (int kt = 0; kt < HID / BK; ++kt) {
    const int ko = kt * BK;
    STAGE(ga0 + ko, la0);
    STAGE(ga1 + ko, la1);
    STAGE(gb0 + ko, lb0);
    STAGE(gb1 + ko, lb1);
    __syncthreads();
    short8 af[4], bfr[4];
#pragma unroll
    for (int m = 0; m < 4; ++m)
      af[m] = *(const short8*)&As[(wm * 64 + m * 16 + fr) * BK + fg * 8];
#pragma unroll
    for (int n = 0; n < 4; ++n)
      bfr[n] = *(const short8*)&Bs[(wn * 64 + n * 16 + fr) * BK + fg * 8];
#pragma unroll
    for (int m = 0; m < 4; ++m)
#pragma unroll
      for (int n = 0; n < 4; ++n)
        acc[m][n] = __builtin_amdgcn_mfma_f32_16x16x32_bf16(af[m], bfr[n], acc[m][n], 0, 0, 0);
    __syncthreads();
  }

  // epilogue: pair adjacent 16-col fragments (gate, up), silu*up*cw -> act bf16
#pragma unroll
  for (int m = 0; m < 4; ++m) {
#pragma unroll
    for (int p = 0; p < 2; ++p) {
      f32x4 g = acc[m][2 * p], u = acc[m][2 * p + 1];
      const int ab = blockIdx.y * 4 + wn * 2 + p;  // act 16-col block
      const int col = ab * 16 + fr;
#pragma unroll
      for (int r = 0; r < 4; ++r) {
        const int row_l = wm * 64 + m * 16 + fg * 4 + r;
        float gate = g[r], up = u[r];
        float s = gate / (1.f + expf(-gate));
        float val = s * up * cws[row_l];
        act[((size_t)e * T_TOK + brow + row_l) * ISZ + col] = f2bf(val);
      }
    }
  }
}

// ---------------- GEMM2: out = sum_e act[e] @ wdT[e]  (K = 9*512) ----------------
__global__ __launch_bounds__(256) void k_gemm_down(
    const u16* __restrict__ act,   // [NE][T][ISZ] bf16 (pre-scaled)
    const u16* __restrict__ wdT,   // [NE][HID][ISZ] bf16
    float* __restrict__ out)       // [T][HID] f32
{
  __shared__ __align__(16) u16 As[BM * BK];
  __shared__ __align__(16) u16 Bs[BN * BK];

  const int tid = threadIdx.x;
  const int w = tid >> 6, l = tid & 63;
  const int brow = blockIdx.x * BM;
  const int bcol = blockIdx.y * BN;

  const int sub = l >> 2;
  const int kc  = (l & 3) * 8;

  const u16* pa0 = act + (size_t)(brow + (w * 2 + 0) * 16 + sub) * ISZ + kc;
  const u16* pa1 = act + (size_t)(brow + (w * 2 + 1) * 16 + sub) * ISZ + kc;
  const u16* pb0 = wdT + (size_t)(bcol + (w * 2 + 0) * 16 + sub) * ISZ + kc;
  const u16* pb1 = wdT + (size_t)(bcol + (w * 2 + 1) * 16 + sub) * ISZ + kc;

  u16* la0 = &As[(w * 2 + 0) * 16 * BK];
  u16* la1 = &As[(w * 2 + 1) * 16 * BK];
  u16* lb0 = &Bs[(w * 2 + 0) * 16 * BK];
  u16* lb1 = &Bs[(w * 2 + 1) * 16 * BK];

  const int wm = w >> 1, wn = w & 1;
  const int fr = l & 15, fg = l >> 4;

  f32x4 acc[4][4];
#pragma unroll
  for (int m = 0; m < 4; ++m)
#pragma unroll
    for (int n = 0; n < 4; ++n) acc[m][n] = (f32x4){0.f, 0.f, 0.f, 0.f};

  for (int kt = 0; kt < (NE * ISZ) / BK; ++kt) {   // 144 iters
    const int e = kt >> 4;                 // 16 K-tiles per expert
    const size_t offA = (size_t)e * T_TOK * ISZ + (size_t)(kt & 15) * BK;
    const size_t offB = (size_t)e * HID * ISZ + (size_t)(kt & 15) * BK;
    STAGE(pa0 + offA, la0);
    STAGE(pa1 + offA, la1);
    STAGE(pb0 + offB, lb0);
    STAGE(pb1 + offB, lb1);
    __syncthreads();
    short8 af[4], bfr[4];
#pragma unroll
    for (int m = 0; m < 4; ++m)
      af[m] = *(const short8*)&As[(wm * 64 + m * 16 + fr) * BK + fg * 8];
#pragma unroll
    for (int n = 0; n < 4; ++n)
      bfr[n] = *(const short8*)&Bs[(wn * 64 + n * 16 + fr) * BK + fg * 8];
#pragma unroll
    for (int m = 0; m < 4; ++m)
#pragma unroll
      for (int n = 0; n < 4; ++n)
        acc[m][n] = __builtin_amdgcn_mfma_f32_16x16x32_bf16(af[m], bfr[n], acc[m][n], 0, 0, 0);
    __syncthreads();
  }

#pragma unroll
  for (int m = 0; m < 4; ++m)
#pragma unroll
    for (int n = 0; n < 4; ++n)
#pragma unroll
      for (int r = 0; r < 4; ++r)
        out[(size_t)(brow + wm * 64 + m * 16 + fg * 4 + r) * HID +
            bcol + wn * 64 + n * 16 + fr] = acc[m][n][r];
}

// ---------------- launch ----------------
extern "C" void kernel_launch(void* const* d_in, const int* in_sizes, int n_in,
                              void* d_out, int out_size, void* d_ws, size_t ws_size,
                              hipStream_t stream) {
  const float* x   = (const float*)d_in[0];
  const float* wg  = (const float*)d_in[1];
  const float* wgu = (const float*)d_in[2];
  const float* wdn = (const float*)d_in[3];
  const float* wsg = (const float*)d_in[4];
  const float* wsd = (const float*)d_in[5];
  float* out = (float*)d_out;

  char* ws = (char*)d_ws;
  u16* xb    = (u16*)ws;  ws += (size_t)T_TOK * HID * 2;
  u16* wgupT = (u16*)ws;  ws += (size_t)NE * 1024 * HID * 2;
  u16* wdT   = (u16*)ws;  ws += (size_t)NE * HID * ISZ * 2;
  u16* actb  = (u16*)ws;  ws += (size_t)NE * T_TOK * ISZ * 2;
  float* cw  = (float*)ws;

  k_cvt_x<<<(T_TOK * HID / 4 + 255) / 256, 256, 0, stream>>>(x, xb, T_TOK * HID / 4);
  k_cvt_wgup<<<dim3(32, 32, NE), dim3(32, 8), 0, stream>>>(wgu, wsg, wgupT);
  k_cvt_wdown<<<dim3(32, 16, NE), dim3(32, 8), 0, stream>>>(wdn, wsd, wdT);
  k_router<<<T_TOK, 64, 0, stream>>>(x, wg, cw);
  k_gemm_gu<<<dim3(T_TOK / BM, 1024 / BN, NE), 256, 0, stream>>>(xb, wgupT, cw, actb);
  k_gemm_down<<<dim3(T_TOK / BM, HID / BN), 256, 0, stream>>>(actb, wdT, out);
}